// Round 8
// baseline (240.850 us; speedup 1.0000x reference)
//
#include <hip/hip_runtime.h>

#define DM 128
#define NHEADS 8

typedef __attribute__((ext_vector_type(8))) __bf16 bf16x8;
typedef __attribute__((ext_vector_type(4))) float f32x4;

__device__ inline unsigned short f2bf(float f) {
    unsigned u = __float_as_uint(f);
    u += 0x7FFFu + ((u >> 16) & 1u);
    return (unsigned short)(u >> 16);
}

// ---------- prep: weight->bf16 conversion (blocks 0..63) + offset scan (block 64) ----------
__global__ void prep(const int* __restrict__ agents, int B,
                     const float* __restrict__ wqkv, const float* __restrict__ wout,
                     int* __restrict__ offs,
                     unsigned short* __restrict__ wqkv_bf,
                     unsigned short* __restrict__ wout_bf) {
    if (blockIdx.x < 64) {
        int idx = (blockIdx.x * 256 + threadIdx.x) * 4;   // 0..65532
        if (idx < 49152) {
            float4 v = *(const float4*)(wqkv + idx);
            ushort4 o;
            o.x = f2bf(v.x); o.y = f2bf(v.y); o.z = f2bf(v.z); o.w = f2bf(v.w);
            *(ushort4*)(wqkv_bf + idx) = o;
        } else {
            int j = idx - 49152;
            float4 v = *(const float4*)(wout + j);
            ushort4 o;
            o.x = f2bf(v.x); o.y = f2bf(v.y); o.z = f2bf(v.z); o.w = f2bf(v.w);
            *(ushort4*)(wout_bf + j) = o;
        }
    } else {
        __shared__ int part[256];
        const int tid = threadIdx.x;
        const int per = (B + 255) >> 8;
        const int base = tid * per;
        int s = 0;
        for (int i = 0; i < per; ++i) {
            int idx = base + i;
            if (idx < B) s += agents[idx];
        }
        part[tid] = s;
        __syncthreads();
        for (int off = 1; off < 256; off <<= 1) {
            int v = (tid >= off) ? part[tid - off] : 0;
            __syncthreads();
            part[tid] += v;
            __syncthreads();
        }
        int run = (tid == 0) ? 0 : part[tid - 1];
        for (int i = 0; i < per; ++i) {
            int idx = base + i;
            if (idx < B) { offs[idx] = run; run += agents[idx]; }
        }
    }
}

// ---------- kernel 1: qkv GEMM. 64-row strip/block; A staged once; B streamed from L2. ----------
__launch_bounds__(256, 4)
__global__ void qkv_gemm(const float* __restrict__ x,
                         const unsigned short* __restrict__ wqkvb,
                         const float* __restrict__ bqkv,
                         unsigned short* __restrict__ qws,   // [M][128] bf16
                         unsigned short* __restrict__ kv,    // [M][256] bf16 (K|V)
                         int M) {
    __shared__ __align__(16) unsigned short As[64 * 136];
    const int m0 = blockIdx.x * 64;
    const int tid = threadIdx.x;

    for (int f = tid; f < 2048; f += 256) {          // A: 64 rows x 128 fp32 -> bf16 (zero pad)
        int t = f >> 5, c = f & 31;
        ushort4 o = make_ushort4(0, 0, 0, 0);
        if (m0 + t < M) {
            float4 v = ((const float4*)(x + (size_t)(m0 + t) * DM))[c];
            o.x = f2bf(v.x); o.y = f2bf(v.y); o.z = f2bf(v.z); o.w = f2bf(v.w);
        }
        *(ushort4*)&As[t * 136 + c * 4] = o;
    }
    __syncthreads();                                  // the ONLY barrier

    const int wave = tid >> 6, lane = tid & 63, quad = lane >> 4, l16 = lane & 15;
    const int mr = wave * 16;
    bf16x8 af[4];
    #pragma unroll
    for (int ks = 0; ks < 4; ++ks)
        af[ks] = *(const bf16x8*)&As[(mr + l16) * 136 + ks * 32 + quad * 8];

    #pragma unroll 2
    for (int ct = 0; ct < 24; ++ct) {                // all 384 output cols
        const int gc = ct * 16 + l16;
        f32x4 acc = {0.f, 0.f, 0.f, 0.f};
        #pragma unroll
        for (int ks = 0; ks < 4; ++ks) {
            bf16x8 bb = *(const bf16x8*)(wqkvb + (size_t)gc * DM + ks * 32 + quad * 8);
            acc = __builtin_amdgcn_mfma_f32_16x16x32_bf16(af[ks], bb, acc, 0, 0, 0);
        }
        const float bias = bqkv[gc];
        #pragma unroll
        for (int r = 0; r < 4; ++r) {
            int row = m0 + mr + quad * 4 + r;
            if (row < M) {
                unsigned short v = f2bf(acc[r] + bias);
                if (gc < 128)       qws[(size_t)row * 128 + gc] = v;
                else if (gc < 256)  kv[(size_t)row * 256 + (gc - 128)] = v;
                else                kv[(size_t)row * 256 + 128 + (gc - 256)] = v;
            }
        }
    }
}

// ---------- kernel 2: attention. 1 block/sample, 8 waves (1/head), LDS-staged Q/K/Vt ----------
// LDS: Qs[64][136] | Ks[64][136] | Vt[128][72] | Ps[8][16][72]  = 71680 B -> 2 blocks/CU
#define QS_OFF 0
#define KS_OFF 17408
#define VT2_OFF 34816
#define PS_OFF 53248
#define SMEM2 71680

__launch_bounds__(512, 4)
__global__ void attn(unsigned short* __restrict__ qa,       // in: Q [M][128]; out: attn (same buf)
                     const unsigned short* __restrict__ kv, // [M][256] K|V
                     const int* __restrict__ agents,
                     const int* __restrict__ offs) {
    __shared__ __align__(16) char smem[SMEM2];
    unsigned short* Qs = (unsigned short*)(smem + QS_OFF);
    unsigned short* Ks = (unsigned short*)(smem + KS_OFF);
    unsigned short* Vt = (unsigned short*)(smem + VT2_OFF);
    unsigned short* Ps = (unsigned short*)(smem + PS_OFF);

    const int s = blockIdx.x;
    const int n = agents[s];
    const int base = offs[s];
    const int tid = threadIdx.x;
    const int wave = tid >> 6, lane = tid & 63, quad = lane >> 4, l16 = lane & 15;
    const int h = wave;                      // one wave per head
    const int nkt = (n + 15) >> 4;           // 16-key tiles
    const int nks = (n + 31) >> 5;           // 32-key groups

    // zero ENTIRE smem (R6 known-good; R7's Vt+Ps-only reduction coincided
    // with a NaN failure -- bisecting: full zero restored, GEMMs kept new)
    for (int f = tid; f < 4480; f += 512)
        ((uint4*)smem)[f] = make_uint4(0u, 0u, 0u, 0u);
    __syncthreads();

    // stage full Q, K rows (128 bf16 = 16 uint4 each), V transposed (scalar u16)
    for (int f = tid; f < n * 16; f += 512) {
        int t = f >> 4, c = f & 15;
        *(uint4*)&Qs[t * 136 + c * 8] = *(const uint4*)(qa + (size_t)(base + t) * 128 + c * 8);
        *(uint4*)&Ks[t * 136 + c * 8] = *(const uint4*)(kv + (size_t)(base + t) * 256 + c * 8);
    }
    for (int f = tid; f < n * 32; f += 512) {
        int t = f >> 5, c4 = f & 31;
        ushort4 vv = *(const ushort4*)(kv + (size_t)(base + t) * 256 + 128 + c4 * 4);
        Vt[(c4 * 4 + 0) * 72 + t] = vv.x;
        Vt[(c4 * 4 + 1) * 72 + t] = vv.y;
        Vt[(c4 * 4 + 2) * 72 + t] = vv.z;
        Vt[(c4 * 4 + 3) * 72 + t] = vv.w;
    }
    __syncthreads();   // after this, the global Q rows of this sample are free to overwrite

    unsigned short* Pw = Ps + wave * 16 * 72;
    for (int mt = 0; mt < nkt; ++mt) {       // query tiles (same count as key tiles)
        bf16x8 qf = (bf16x8)(__bf16)0.0f;
        if (quad < 2)
            qf = *(const bf16x8*)&Qs[(mt * 16 + l16) * 136 + h * 16 + quad * 8];
        f32x4 sc[4];
        #pragma unroll
        for (int kt = 0; kt < 4; ++kt)
            sc[kt] = (f32x4){0.f, 0.f, 0.f, 0.f};
        #pragma unroll
        for (int kt = 0; kt < 4; ++kt) {
            if (kt < nkt) {
                bf16x8 bb = *(const bf16x8*)&Ks[(kt * 16 + l16) * 136 + h * 16 + quad * 8];
                sc[kt] = __builtin_amdgcn_mfma_f32_16x16x32_bf16(qf, bb,
                          (f32x4){0.f, 0.f, 0.f, 0.f}, 0, 0, 0);
            }
        }
        #pragma unroll
        for (int r = 0; r < 4; ++r) {
            float pr[4];
            float mm = -1e30f;
            #pragma unroll
            for (int kt = 0; kt < 4; ++kt) {
                float v = -1e30f;
                if (kt < nkt) {
                    int key = kt * 16 + l16;
                    v = (key < n) ? sc[kt][r] * 0.25f : -1e30f;   // scale = 1/sqrt(16)
                }
                pr[kt] = v;
                mm = fmaxf(mm, v);
            }
            mm = fmaxf(mm, __shfl_xor(mm, 1));
            mm = fmaxf(mm, __shfl_xor(mm, 2));
            mm = fmaxf(mm, __shfl_xor(mm, 4));
            mm = fmaxf(mm, __shfl_xor(mm, 8));
            float ll = 0.f;
            #pragma unroll
            for (int kt = 0; kt < 4; ++kt) {
                if (kt < nkt) {
                    float e = __expf(pr[kt] - mm);
                    pr[kt] = e;
                    ll += e;
                }
            }
            ll += __shfl_xor(ll, 1);
            ll += __shfl_xor(ll, 2);
            ll += __shfl_xor(ll, 4);
            ll += __shfl_xor(ll, 8);
            float inv = 1.0f / ll;
            #pragma unroll
            for (int kt = 0; kt < 4; ++kt)
                if (kt < nkt)
                    Pw[(quad * 4 + r) * 72 + kt * 16 + l16] = f2bf(pr[kt] * inv);
        }
        // PV
        f32x4 o = {0.f, 0.f, 0.f, 0.f};
        #pragma unroll
        for (int ks = 0; ks < 2; ++ks) {
            if (ks < nks) {
                bf16x8 a = *(const bf16x8*)&Pw[l16 * 72 + ks * 32 + quad * 8];
                bf16x8 bb = *(const bf16x8*)&Vt[(h * 16 + l16) * 72 + ks * 32 + quad * 8];
                o = __builtin_amdgcn_mfma_f32_16x16x32_bf16(a, bb, o, 0, 0, 0);
            }
        }
        #pragma unroll
        for (int r = 0; r < 4; ++r) {
            int row = mt * 16 + quad * 4 + r;
            if (row < n)
                qa[(size_t)(base + row) * 128 + h * 16 + l16] = f2bf(o[r]);
        }
    }
}

// ---------- kernel 3: out-proj GEMM. A staged once; Wout streamed from L2. ----------
__launch_bounds__(256, 4)
__global__ void oproj(const unsigned short* __restrict__ attn_b,  // [M][128] bf16 (ws)
                      const unsigned short* __restrict__ woutb,
                      const float* __restrict__ bout,
                      float* __restrict__ out, int M) {
    __shared__ __align__(16) unsigned short As[64 * 136];
    const int m0 = blockIdx.x * 64;
    const int tid = threadIdx.x;

    for (int f = tid; f < 1024; f += 256) {          // A tile (zero pad beyond M)
        int t = f >> 4, c = f & 15;
        uint4 w = make_uint4(0u, 0u, 0u, 0u);
        if (m0 + t < M)
            w = *(const uint4*)(attn_b + (size_t)(m0 + t) * DM + c * 8);
        *(uint4*)&As[t * 136 + c * 8] = w;
    }
    __syncthreads();                                  // the ONLY barrier

    const int wave = tid >> 6, lane = tid & 63, quad = lane >> 4, l16 = lane & 15;
    const int mr = wave * 16;
    bf16x8 af[4];
    #pragma unroll
    for (int ks = 0; ks < 4; ++ks)
        af[ks] = *(const bf16x8*)&As[(mr + l16) * 136 + ks * 32 + quad * 8];

    #pragma unroll 2
    for (int ct = 0; ct < 8; ++ct) {
        const int gc = ct * 16 + l16;
        f32x4 acc = {0.f, 0.f, 0.f, 0.f};
        #pragma unroll
        for (int ks = 0; ks < 4; ++ks) {
            bf16x8 bb = *(const bf16x8*)(woutb + (size_t)gc * DM + ks * 32 + quad * 8);
            acc = __builtin_amdgcn_mfma_f32_16x16x32_bf16(af[ks], bb, acc, 0, 0, 0);
        }
        const float bias = bout[gc];
        #pragma unroll
        for (int r = 0; r < 4; ++r) {
            int row = m0 + mr + quad * 4 + r;
            if (row < M)
                out[(size_t)row * DM + gc] = acc[r] + bias;
        }
    }
}

extern "C" void kernel_launch(void* const* d_in, const int* in_sizes, int n_in,
                              void* d_out, int out_size, void* d_ws, size_t ws_size,
                              hipStream_t stream) {
    const float* att_in     = (const float*)d_in[0];
    const float* in_proj_w  = (const float*)d_in[1];
    const float* in_proj_b  = (const float*)d_in[2];
    const float* out_proj_w = (const float*)d_in[3];
    const float* out_proj_b = (const float*)d_in[4];
    const int*   agents     = (const int*)d_in[5];
    const int B = in_sizes[5];
    const int M = out_size / DM;             // total tokens (66560)

    // ws layout (assumes ws_size >= ~17.2 MB):
    //   [0,8192)            offs
    //   [8192,106496)       wqkv bf16
    //   [106496,139264)     wout bf16
    //   [139264, +M*256)    Q bf16, later attn_out bf16 (overwritten in-place by attn)
    int* offs = (int*)d_ws;
    unsigned short* wqkv_bf = (unsigned short*)((char*)d_ws + 8192);
    unsigned short* wout_bf = (unsigned short*)((char*)d_ws + 106496);
    unsigned short* qbuf    = (unsigned short*)((char*)d_ws + 139264);
    unsigned short* kvbuf   = (unsigned short*)d_out;   // [M][256] bf16 == exactly out bytes

    hipLaunchKernelGGL(prep, dim3(65), dim3(256), 0, stream,
                       agents, B, in_proj_w, out_proj_w, offs, wqkv_bf, wout_bf);
    hipLaunchKernelGGL(qkv_gemm, dim3((M + 63) / 64), dim3(256), 0, stream,
                       att_in, wqkv_bf, in_proj_b, qbuf, kvbuf, M);
    hipLaunchKernelGGL(attn, dim3(B), dim3(512), 0, stream,
                       qbuf, kvbuf, agents, offs);
    hipLaunchKernelGGL(oproj, dim3((M + 63) / 64), dim3(256), 0, stream,
                       qbuf, wout_bf, out_proj_b, (float*)d_out, M);
}

// Round 9
// 218.141 us; speedup vs baseline: 1.1041x; 1.1041x over previous
//
#include <hip/hip_runtime.h>

#define DM 128
#define NHEADS 8

typedef __attribute__((ext_vector_type(8))) __bf16 bf16x8;
typedef __attribute__((ext_vector_type(4))) float f32x4;

__device__ inline unsigned short f2bf(float f) {
    unsigned u = __float_as_uint(f);
    u += 0x7FFFu + ((u >> 16) & 1u);
    return (unsigned short)(u >> 16);
}

// ---------- prep: weight->bf16 conversion (blocks 0..63) + offset scan (block 64) ----------
__global__ void prep(const int* __restrict__ agents, int B,
                     const float* __restrict__ wqkv, const float* __restrict__ wout,
                     int* __restrict__ offs,
                     unsigned short* __restrict__ wqkv_bf,
                     unsigned short* __restrict__ wout_bf) {
    if (blockIdx.x < 64) {
        int idx = (blockIdx.x * 256 + threadIdx.x) * 4;   // 0..65532
        if (idx < 49152) {
            float4 v = *(const float4*)(wqkv + idx);
            ushort4 o;
            o.x = f2bf(v.x); o.y = f2bf(v.y); o.z = f2bf(v.z); o.w = f2bf(v.w);
            *(ushort4*)(wqkv_bf + idx) = o;
        } else {
            int j = idx - 49152;
            float4 v = *(const float4*)(wout + j);
            ushort4 o;
            o.x = f2bf(v.x); o.y = f2bf(v.y); o.z = f2bf(v.z); o.w = f2bf(v.w);
            *(ushort4*)(wout_bf + j) = o;
        }
    } else {
        __shared__ int part[256];
        const int tid = threadIdx.x;
        const int per = (B + 255) >> 8;
        const int base = tid * per;
        int s = 0;
        for (int i = 0; i < per; ++i) {
            int idx = base + i;
            if (idx < B) s += agents[idx];
        }
        part[tid] = s;
        __syncthreads();
        for (int off = 1; off < 256; off <<= 1) {
            int v = (tid >= off) ? part[tid - off] : 0;
            __syncthreads();
            part[tid] += v;
            __syncthreads();
        }
        int run = (tid == 0) ? 0 : part[tid - 1];
        for (int i = 0; i < per; ++i) {
            int idx = base + i;
            if (idx < B) { offs[idx] = run; run += agents[idx]; }
        }
    }
}

// ---------- kernel 1: qkv GEMM. 128-row strip/block; A in LDS; B prefetch-streamed from L2. ----------
__launch_bounds__(256, 4)
__global__ void qkv_gemm(const float* __restrict__ x,
                         const unsigned short* __restrict__ wqkvb,
                         const float* __restrict__ bqkv,
                         unsigned short* __restrict__ qws,   // [M][128] bf16
                         unsigned short* __restrict__ kv,    // [M][256] bf16 (K|V)
                         int M) {
    __shared__ __align__(16) unsigned short As[128 * 136];   // 34816 B
    const int m0 = blockIdx.x * 128;
    const int tid = threadIdx.x;

    for (int f = tid; f < 4096; f += 256) {          // A: 128 rows x 128 fp32 -> bf16 (zero pad)
        int t = f >> 5, c = f & 31;
        ushort4 o = make_ushort4(0, 0, 0, 0);
        if (m0 + t < M) {
            float4 v = ((const float4*)(x + (size_t)(m0 + t) * DM))[c];
            o.x = f2bf(v.x); o.y = f2bf(v.y); o.z = f2bf(v.z); o.w = f2bf(v.w);
        }
        *(ushort4*)&As[t * 136 + c * 4] = o;
    }
    __syncthreads();                                  // the ONLY barrier

    const int wave = tid >> 6, lane = tid & 63, quad = lane >> 4, l16 = lane & 15;
    const int mr = wave * 32;                         // each wave: 2 M-tiles (32 rows)
    bf16x8 af[2][4];
    #pragma unroll
    for (int mt = 0; mt < 2; ++mt)
        #pragma unroll
        for (int ks = 0; ks < 4; ++ks)
            af[mt][ks] = *(const bf16x8*)&As[(mr + mt * 16 + l16) * 136 + ks * 32 + quad * 8];

    // software pipeline: B-frags for ct+1 load while ct computes
    bf16x8 bp[4];
    #pragma unroll
    for (int ks = 0; ks < 4; ++ks)
        bp[ks] = *(const bf16x8*)(wqkvb + (size_t)l16 * DM + ks * 32 + quad * 8);

    for (int ct = 0; ct < 24; ++ct) {
        bf16x8 bc[4];
        #pragma unroll
        for (int ks = 0; ks < 4; ++ks) bc[ks] = bp[ks];
        if (ct < 23) {
            const int gn = (ct + 1) * 16 + l16;
            #pragma unroll
            for (int ks = 0; ks < 4; ++ks)
                bp[ks] = *(const bf16x8*)(wqkvb + (size_t)gn * DM + ks * 32 + quad * 8);
        }
        f32x4 a0 = {0.f, 0.f, 0.f, 0.f}, a1 = {0.f, 0.f, 0.f, 0.f};
        #pragma unroll
        for (int ks = 0; ks < 4; ++ks) {
            a0 = __builtin_amdgcn_mfma_f32_16x16x32_bf16(af[0][ks], bc[ks], a0, 0, 0, 0);
            a1 = __builtin_amdgcn_mfma_f32_16x16x32_bf16(af[1][ks], bc[ks], a1, 0, 0, 0);
        }
        const int gc = ct * 16 + l16;
        const float bias = bqkv[gc];
        #pragma unroll
        for (int r = 0; r < 4; ++r) {
            int row0 = m0 + mr + quad * 4 + r;
            int row1 = row0 + 16;
            unsigned short v0 = f2bf(a0[r] + bias);
            unsigned short v1 = f2bf(a1[r] + bias);
            if (gc < 128) {
                if (row0 < M) qws[(size_t)row0 * 128 + gc] = v0;
                if (row1 < M) qws[(size_t)row1 * 128 + gc] = v1;
            } else if (gc < 256) {
                if (row0 < M) kv[(size_t)row0 * 256 + (gc - 128)] = v0;
                if (row1 < M) kv[(size_t)row1 * 256 + (gc - 128)] = v1;
            } else {
                if (row0 < M) kv[(size_t)row0 * 256 + 128 + (gc - 256)] = v0;
                if (row1 < M) kv[(size_t)row1 * 256 + 128 + (gc - 256)] = v1;
            }
        }
    }
}

// ---------- kernel 2: attention. 1 block/sample, 8 waves (1/head), LDS-staged Q/K/Vt ----------
// LDS: Qs[64][136] | Ks[64][136] | Vt[128][72] | Ps[8][16][72]  = 71680 B -> 2 blocks/CU
#define QS_OFF 0
#define KS_OFF 17408
#define VT2_OFF 34816
#define PS_OFF 53248
#define SMEM2 71680

__launch_bounds__(512, 4)
__global__ void attn(unsigned short* __restrict__ qa,       // in: Q [M][128]; out: attn (same buf)
                     const unsigned short* __restrict__ kv, // [M][256] K|V
                     const int* __restrict__ agents,
                     const int* __restrict__ offs) {
    __shared__ __align__(16) char smem[SMEM2];
    unsigned short* Qs = (unsigned short*)(smem + QS_OFF);
    unsigned short* Ks = (unsigned short*)(smem + KS_OFF);
    unsigned short* Vt = (unsigned short*)(smem + VT2_OFF);
    unsigned short* Ps = (unsigned short*)(smem + PS_OFF);

    const int s = blockIdx.x;
    const int n = agents[s];
    const int base = offs[s];
    const int tid = threadIdx.x;
    const int wave = tid >> 6, lane = tid & 63, quad = lane >> 4, l16 = lane & 15;
    const int h = wave;                      // one wave per head
    const int nkt = (n + 15) >> 4;           // 16-key tiles
    const int nks = (n + 31) >> 5;           // 32-key groups

    // zero ENTIRE smem (R8 bisection: every LDS byte an MFMA can touch gets zeroed)
    for (int f = tid; f < 4480; f += 512)
        ((uint4*)smem)[f] = make_uint4(0u, 0u, 0u, 0u);
    __syncthreads();

    // stage full Q, K rows (128 bf16 = 16 uint4 each), V transposed (scalar u16)
    for (int f = tid; f < n * 16; f += 512) {
        int t = f >> 4, c = f & 15;
        *(uint4*)&Qs[t * 136 + c * 8] = *(const uint4*)(qa + (size_t)(base + t) * 128 + c * 8);
        *(uint4*)&Ks[t * 136 + c * 8] = *(const uint4*)(kv + (size_t)(base + t) * 256 + c * 8);
    }
    for (int f = tid; f < n * 32; f += 512) {
        int t = f >> 5, c4 = f & 31;
        ushort4 vv = *(const ushort4*)(kv + (size_t)(base + t) * 256 + 128 + c4 * 4);
        Vt[(c4 * 4 + 0) * 72 + t] = vv.x;
        Vt[(c4 * 4 + 1) * 72 + t] = vv.y;
        Vt[(c4 * 4 + 2) * 72 + t] = vv.z;
        Vt[(c4 * 4 + 3) * 72 + t] = vv.w;
    }
    __syncthreads();   // after this, the global Q rows of this sample are free to overwrite

    unsigned short* Pw = Ps + wave * 16 * 72;
    for (int mt = 0; mt < nkt; ++mt) {       // query tiles (same count as key tiles)
        bf16x8 qf = (bf16x8)(__bf16)0.0f;
        if (quad < 2)
            qf = *(const bf16x8*)&Qs[(mt * 16 + l16) * 136 + h * 16 + quad * 8];
        f32x4 sc[4];
        #pragma unroll
        for (int kt = 0; kt < 4; ++kt)
            sc[kt] = (f32x4){0.f, 0.f, 0.f, 0.f};
        #pragma unroll
        for (int kt = 0; kt < 4; ++kt) {
            if (kt < nkt) {
                bf16x8 bb = *(const bf16x8*)&Ks[(kt * 16 + l16) * 136 + h * 16 + quad * 8];
                sc[kt] = __builtin_amdgcn_mfma_f32_16x16x32_bf16(qf, bb,
                          (f32x4){0.f, 0.f, 0.f, 0.f}, 0, 0, 0);
            }
        }
        #pragma unroll
        for (int r = 0; r < 4; ++r) {
            float pr[4];
            float mm = -1e30f;
            #pragma unroll
            for (int kt = 0; kt < 4; ++kt) {
                float v = -1e30f;
                if (kt < nkt) {
                    int key = kt * 16 + l16;
                    v = (key < n) ? sc[kt][r] * 0.25f : -1e30f;   // scale = 1/sqrt(16)
                }
                pr[kt] = v;
                mm = fmaxf(mm, v);
            }
            mm = fmaxf(mm, __shfl_xor(mm, 1));
            mm = fmaxf(mm, __shfl_xor(mm, 2));
            mm = fmaxf(mm, __shfl_xor(mm, 4));
            mm = fmaxf(mm, __shfl_xor(mm, 8));
            float ll = 0.f;
            #pragma unroll
            for (int kt = 0; kt < 4; ++kt) {
                if (kt < nkt) {
                    float e = __expf(pr[kt] - mm);
                    pr[kt] = e;
                    ll += e;
                }
            }
            ll += __shfl_xor(ll, 1);
            ll += __shfl_xor(ll, 2);
            ll += __shfl_xor(ll, 4);
            ll += __shfl_xor(ll, 8);
            float inv = 1.0f / ll;
            #pragma unroll
            for (int kt = 0; kt < 4; ++kt)
                if (kt < nkt)
                    Pw[(quad * 4 + r) * 72 + kt * 16 + l16] = f2bf(pr[kt] * inv);
        }
        // PV
        f32x4 o = {0.f, 0.f, 0.f, 0.f};
        #pragma unroll
        for (int ks = 0; ks < 2; ++ks) {
            if (ks < nks) {
                bf16x8 a = *(const bf16x8*)&Pw[l16 * 72 + ks * 32 + quad * 8];
                bf16x8 bb = *(const bf16x8*)&Vt[(h * 16 + l16) * 72 + ks * 32 + quad * 8];
                o = __builtin_amdgcn_mfma_f32_16x16x32_bf16(a, bb, o, 0, 0, 0);
            }
        }
        #pragma unroll
        for (int r = 0; r < 4; ++r) {
            int row = mt * 16 + quad * 4 + r;
            if (row < n)
                qa[(size_t)(base + row) * 128 + h * 16 + l16] = f2bf(o[r]);
        }
    }
}

// ---------- kernel 3: out-proj GEMM. 128-row strip/block; Wout prefetch-streamed. ----------
__launch_bounds__(256, 4)
__global__ void oproj(const unsigned short* __restrict__ attn_b,  // [M][128] bf16 (ws)
                      const unsigned short* __restrict__ woutb,
                      const float* __restrict__ bout,
                      float* __restrict__ out, int M) {
    __shared__ __align__(16) unsigned short As[128 * 136];
    const int m0 = blockIdx.x * 128;
    const int tid = threadIdx.x;

    for (int f = tid; f < 2048; f += 256) {          // A tile (zero pad beyond M)
        int t = f >> 4, c = f & 15;
        uint4 w = make_uint4(0u, 0u, 0u, 0u);
        if (m0 + t < M)
            w = *(const uint4*)(attn_b + (size_t)(m0 + t) * DM + c * 8);
        *(uint4*)&As[t * 136 + c * 8] = w;
    }
    __syncthreads();                                  // the ONLY barrier

    const int wave = tid >> 6, lane = tid & 63, quad = lane >> 4, l16 = lane & 15;
    const int mr = wave * 32;
    bf16x8 af[2][4];
    #pragma unroll
    for (int mt = 0; mt < 2; ++mt)
        #pragma unroll
        for (int ks = 0; ks < 4; ++ks)
            af[mt][ks] = *(const bf16x8*)&As[(mr + mt * 16 + l16) * 136 + ks * 32 + quad * 8];

    bf16x8 bp[4];
    #pragma unroll
    for (int ks = 0; ks < 4; ++ks)
        bp[ks] = *(const bf16x8*)(woutb + (size_t)l16 * DM + ks * 32 + quad * 8);

    for (int ct = 0; ct < 8; ++ct) {
        bf16x8 bc[4];
        #pragma unroll
        for (int ks = 0; ks < 4; ++ks) bc[ks] = bp[ks];
        if (ct < 7) {
            const int gn = (ct + 1) * 16 + l16;
            #pragma unroll
            for (int ks = 0; ks < 4; ++ks)
                bp[ks] = *(const bf16x8*)(woutb + (size_t)gn * DM + ks * 32 + quad * 8);
        }
        f32x4 a0 = {0.f, 0.f, 0.f, 0.f}, a1 = {0.f, 0.f, 0.f, 0.f};
        #pragma unroll
        for (int ks = 0; ks < 4; ++ks) {
            a0 = __builtin_amdgcn_mfma_f32_16x16x32_bf16(af[0][ks], bc[ks], a0, 0, 0, 0);
            a1 = __builtin_amdgcn_mfma_f32_16x16x32_bf16(af[1][ks], bc[ks], a1, 0, 0, 0);
        }
        const int gc = ct * 16 + l16;
        const float bias = bout[gc];
        #pragma unroll
        for (int r = 0; r < 4; ++r) {
            int row0 = m0 + mr + quad * 4 + r;
            int row1 = row0 + 16;
            if (row0 < M) out[(size_t)row0 * DM + gc] = a0[r] + bias;
            if (row1 < M) out[(size_t)row1 * DM + gc] = a1[r] + bias;
        }
    }
}

extern "C" void kernel_launch(void* const* d_in, const int* in_sizes, int n_in,
                              void* d_out, int out_size, void* d_ws, size_t ws_size,
                              hipStream_t stream) {
    const float* att_in     = (const float*)d_in[0];
    const float* in_proj_w  = (const float*)d_in[1];
    const float* in_proj_b  = (const float*)d_in[2];
    const float* out_proj_w = (const float*)d_in[3];
    const float* out_proj_b = (const float*)d_in[4];
    const int*   agents     = (const int*)d_in[5];
    const int B = in_sizes[5];
    const int M = out_size / DM;             // total tokens (66560)

    // ws layout (assumes ws_size >= ~17.2 MB):
    //   [0,8192)            offs
    //   [8192,106496)       wqkv bf16
    //   [106496,139264)     wout bf16
    //   [139264, +M*256)    Q bf16, later attn_out bf16 (overwritten in-place by attn)
    int* offs = (int*)d_ws;
    unsigned short* wqkv_bf = (unsigned short*)((char*)d_ws + 8192);
    unsigned short* wout_bf = (unsigned short*)((char*)d_ws + 106496);
    unsigned short* qbuf    = (unsigned short*)((char*)d_ws + 139264);
    unsigned short* kvbuf   = (unsigned short*)d_out;   // [M][256] bf16 == exactly out bytes

    hipLaunchKernelGGL(prep, dim3(65), dim3(256), 0, stream,
                       agents, B, in_proj_w, out_proj_w, offs, wqkv_bf, wout_bf);
    hipLaunchKernelGGL(qkv_gemm, dim3((M + 127) / 128), dim3(256), 0, stream,
                       att_in, wqkv_bf, in_proj_b, qbuf, kvbuf, M);
    hipLaunchKernelGGL(attn, dim3(B), dim3(512), 0, stream,
                       qbuf, kvbuf, agents, offs);
    hipLaunchKernelGGL(oproj, dim3((M + 127) / 128), dim3(256), 0, stream,
                       qbuf, wout_bf, out_proj_b, (float*)d_out, M);
}

// Round 10
// 210.858 us; speedup vs baseline: 1.1422x; 1.0345x over previous
//
#include <hip/hip_runtime.h>

#define DM 128
#define NHEADS 8

typedef __attribute__((ext_vector_type(8))) __bf16 bf16x8;
typedef __attribute__((ext_vector_type(4))) float f32x4;

__device__ inline unsigned short f2bf(float f) {
    unsigned u = __float_as_uint(f);
    u += 0x7FFFu + ((u >> 16) & 1u);
    return (unsigned short)(u >> 16);
}

// ---------- prep: weight->bf16 conversion (blocks 0..63) + offset scan (block 64) ----------
__global__ void prep(const int* __restrict__ agents, int B,
                     const float* __restrict__ wqkv, const float* __restrict__ wout,
                     int* __restrict__ offs,
                     unsigned short* __restrict__ wqkv_bf,
                     unsigned short* __restrict__ wout_bf) {
    if (blockIdx.x < 64) {
        int idx = (blockIdx.x * 256 + threadIdx.x) * 4;   // 0..65532
        if (idx < 49152) {
            float4 v = *(const float4*)(wqkv + idx);
            ushort4 o;
            o.x = f2bf(v.x); o.y = f2bf(v.y); o.z = f2bf(v.z); o.w = f2bf(v.w);
            *(ushort4*)(wqkv_bf + idx) = o;
        } else {
            int j = idx - 49152;
            float4 v = *(const float4*)(wout + j);
            ushort4 o;
            o.x = f2bf(v.x); o.y = f2bf(v.y); o.z = f2bf(v.z); o.w = f2bf(v.w);
            *(ushort4*)(wout_bf + j) = o;
        }
    } else {
        __shared__ int part[256];
        const int tid = threadIdx.x;
        const int per = (B + 255) >> 8;
        const int base = tid * per;
        int s = 0;
        for (int i = 0; i < per; ++i) {
            int idx = base + i;
            if (idx < B) s += agents[idx];
        }
        part[tid] = s;
        __syncthreads();
        for (int off = 1; off < 256; off <<= 1) {
            int v = (tid >= off) ? part[tid - off] : 0;
            __syncthreads();
            part[tid] += v;
            __syncthreads();
        }
        int run = (tid == 0) ? 0 : part[tid - 1];
        for (int i = 0; i < per; ++i) {
            int idx = base + i;
            if (idx < B) { offs[idx] = run; run += agents[idx]; }
        }
    }
}

// ---------- kernel 1: qkv GEMM. 128-row strip/block; A in LDS; B prefetch-streamed from L2. ----------
__launch_bounds__(256, 4)
__global__ void qkv_gemm(const float* __restrict__ x,
                         const unsigned short* __restrict__ wqkvb,
                         const float* __restrict__ bqkv,
                         unsigned short* __restrict__ qws,   // [M][128] bf16
                         unsigned short* __restrict__ kv,    // [M][256] bf16 (K|V)
                         int M) {
    __shared__ __align__(16) unsigned short As[128 * 136];   // 34816 B
    const int m0 = blockIdx.x * 128;
    const int tid = threadIdx.x;

    for (int f = tid; f < 4096; f += 256) {          // A: 128 rows x 128 fp32 -> bf16 (zero pad)
        int t = f >> 5, c = f & 31;
        ushort4 o = make_ushort4(0, 0, 0, 0);
        if (m0 + t < M) {
            float4 v = ((const float4*)(x + (size_t)(m0 + t) * DM))[c];
            o.x = f2bf(v.x); o.y = f2bf(v.y); o.z = f2bf(v.z); o.w = f2bf(v.w);
        }
        *(ushort4*)&As[t * 136 + c * 4] = o;
    }
    __syncthreads();                                  // the ONLY barrier

    const int wave = tid >> 6, lane = tid & 63, quad = lane >> 4, l16 = lane & 15;
    const int mr = wave * 32;                         // each wave: 2 M-tiles (32 rows)
    bf16x8 af[2][4];
    #pragma unroll
    for (int mt = 0; mt < 2; ++mt)
        #pragma unroll
        for (int ks = 0; ks < 4; ++ks)
            af[mt][ks] = *(const bf16x8*)&As[(mr + mt * 16 + l16) * 136 + ks * 32 + quad * 8];

    // software pipeline: B-frags for ct+1 load while ct computes
    bf16x8 bp[4];
    #pragma unroll
    for (int ks = 0; ks < 4; ++ks)
        bp[ks] = *(const bf16x8*)(wqkvb + (size_t)l16 * DM + ks * 32 + quad * 8);

    for (int ct = 0; ct < 24; ++ct) {
        bf16x8 bc[4];
        #pragma unroll
        for (int ks = 0; ks < 4; ++ks) bc[ks] = bp[ks];
        if (ct < 23) {
            const int gn = (ct + 1) * 16 + l16;
            #pragma unroll
            for (int ks = 0; ks < 4; ++ks)
                bp[ks] = *(const bf16x8*)(wqkvb + (size_t)gn * DM + ks * 32 + quad * 8);
        }
        f32x4 a0 = {0.f, 0.f, 0.f, 0.f}, a1 = {0.f, 0.f, 0.f, 0.f};
        #pragma unroll
        for (int ks = 0; ks < 4; ++ks) {
            a0 = __builtin_amdgcn_mfma_f32_16x16x32_bf16(af[0][ks], bc[ks], a0, 0, 0, 0);
            a1 = __builtin_amdgcn_mfma_f32_16x16x32_bf16(af[1][ks], bc[ks], a1, 0, 0, 0);
        }
        const int gc = ct * 16 + l16;
        const float bias = bqkv[gc];
        #pragma unroll
        for (int r = 0; r < 4; ++r) {
            int row0 = m0 + mr + quad * 4 + r;
            int row1 = row0 + 16;
            unsigned short v0 = f2bf(a0[r] + bias);
            unsigned short v1 = f2bf(a1[r] + bias);
            if (gc < 128) {
                if (row0 < M) qws[(size_t)row0 * 128 + gc] = v0;
                if (row1 < M) qws[(size_t)row1 * 128 + gc] = v1;
            } else if (gc < 256) {
                if (row0 < M) kv[(size_t)row0 * 256 + (gc - 128)] = v0;
                if (row1 < M) kv[(size_t)row1 * 256 + (gc - 128)] = v1;
            } else {
                if (row0 < M) kv[(size_t)row0 * 256 + 128 + (gc - 256)] = v0;
                if (row1 < M) kv[(size_t)row1 * 256 + 128 + (gc - 256)] = v1;
            }
        }
    }
}

// ---------- kernel 2: attention. 1 block/sample, 8 waves (1/head). ----------
// LDS: Ks[64][136] | Vs[64][136] (row-major!) | Ps[8][16][72] = 53248 B -> 3 blocks/CU
// Q is NOT staged: each wave loads its Q fragments directly from global (L2-hot).
#define KS_OFF 0
#define VS_OFF 17408
#define PS_OFF 34816
#define SMEM2 53248

__launch_bounds__(512, 6)
__global__ void attn(unsigned short* __restrict__ qa,       // in: Q [M][128]; out: attn (same buf)
                     const unsigned short* __restrict__ kv, // [M][256] K|V
                     const int* __restrict__ agents,
                     const int* __restrict__ offs,
                     int M) {
    __shared__ __align__(16) char smem[SMEM2];
    unsigned short* Ks = (unsigned short*)(smem + KS_OFF);
    unsigned short* Vs = (unsigned short*)(smem + VS_OFF);
    unsigned short* Ps = (unsigned short*)(smem + PS_OFF);

    const int s = blockIdx.x;
    const int n = agents[s];
    const int base = offs[s];
    const int tid = threadIdx.x;
    const int wave = tid >> 6, lane = tid & 63, quad = lane >> 4, l16 = lane & 15;
    const int h = wave;                      // one wave per head
    const int nkt = (n + 15) >> 4;           // 16-key tiles
    const int nks = (n + 31) >> 5;           // 32-key groups

    // zero ENTIRE smem (R8 rule: every LDS byte an MFMA can touch gets zeroed)
    for (int f = tid; f < 3328; f += 512)
        ((uint4*)smem)[f] = make_uint4(0u, 0u, 0u, 0u);
    __syncthreads();

    // stage K and V rows, both row-major (coalesced uint4; no transpose scatter)
    for (int f = tid; f < n * 16; f += 512) {
        int t = f >> 4, c = f & 15;
        *(uint4*)&Ks[t * 136 + c * 8] = *(const uint4*)(kv + (size_t)(base + t) * 256 + c * 8);
        *(uint4*)&Vs[t * 136 + c * 8] = *(const uint4*)(kv + (size_t)(base + t) * 256 + 128 + c * 8);
    }
    __syncthreads();

    unsigned short* Pw = Ps + wave * 16 * 72;
    const __bf16* Vsb = (const __bf16*)Vs;
    for (int mt = 0; mt < nkt; ++mt) {       // query tiles
        // Q fragment direct from global (A-layout, head_dim 16 zero-padded to K=32).
        // Row clamped to M-1: clamped/raced rows are finite and only feed discarded outputs.
        bf16x8 qf = (bf16x8)(__bf16)0.0f;
        if (quad < 2) {
            int qrow = base + mt * 16 + l16;
            qrow = (qrow < M) ? qrow : (M - 1);
            qf = *(const bf16x8*)(qa + (size_t)qrow * 128 + h * 16 + quad * 8);
        }
        f32x4 sc[4];
        #pragma unroll
        for (int kt = 0; kt < 4; ++kt)
            sc[kt] = (f32x4){0.f, 0.f, 0.f, 0.f};
        #pragma unroll
        for (int kt = 0; kt < 4; ++kt) {
            if (kt < nkt) {
                bf16x8 bb = *(const bf16x8*)&Ks[(kt * 16 + l16) * 136 + h * 16 + quad * 8];
                sc[kt] = __builtin_amdgcn_mfma_f32_16x16x32_bf16(qf, bb,
                          (f32x4){0.f, 0.f, 0.f, 0.f}, 0, 0, 0);
            }
        }
        #pragma unroll
        for (int r = 0; r < 4; ++r) {
            float pr[4];
            float mm = -1e30f;
            #pragma unroll
            for (int kt = 0; kt < 4; ++kt) {
                float v = -1e30f;
                if (kt < nkt) {
                    int key = kt * 16 + l16;
                    v = (key < n) ? sc[kt][r] * 0.25f : -1e30f;   // scale = 1/sqrt(16)
                }
                pr[kt] = v;
                mm = fmaxf(mm, v);
            }
            mm = fmaxf(mm, __shfl_xor(mm, 1));
            mm = fmaxf(mm, __shfl_xor(mm, 2));
            mm = fmaxf(mm, __shfl_xor(mm, 4));
            mm = fmaxf(mm, __shfl_xor(mm, 8));
            float ll = 0.f;
            #pragma unroll
            for (int kt = 0; kt < 4; ++kt) {
                if (kt < nkt) {
                    float e = __expf(pr[kt] - mm);
                    pr[kt] = e;
                    ll += e;
                }
            }
            ll += __shfl_xor(ll, 1);
            ll += __shfl_xor(ll, 2);
            ll += __shfl_xor(ll, 4);
            ll += __shfl_xor(ll, 8);
            float inv = 1.0f / ll;
            #pragma unroll
            for (int kt = 0; kt < 4; ++kt)
                if (kt < nkt)
                    Pw[(quad * 4 + r) * 72 + kt * 16 + l16] = f2bf(pr[kt] * inv);
        }
        // PV: A = P (wave-private), B built from row-major Vs by 8 scalar LDS reads:
        // B element (k=quad*8+j, n=l16) = V[tok=ks2*32+quad*8+j][d=h*16+l16]
        f32x4 o = {0.f, 0.f, 0.f, 0.f};
        #pragma unroll
        for (int ks2 = 0; ks2 < 2; ++ks2) {
            if (ks2 < nks) {
                bf16x8 a = *(const bf16x8*)&Pw[l16 * 72 + ks2 * 32 + quad * 8];
                bf16x8 bb;
                #pragma unroll
                for (int j = 0; j < 8; ++j)
                    bb[j] = Vsb[(ks2 * 32 + quad * 8 + j) * 136 + h * 16 + l16];
                o = __builtin_amdgcn_mfma_f32_16x16x32_bf16(a, bb, o, 0, 0, 0);
            }
        }
        #pragma unroll
        for (int r = 0; r < 4; ++r) {
            int row = mt * 16 + quad * 4 + r;
            if (row < n)
                qa[(size_t)(base + row) * 128 + h * 16 + l16] = f2bf(o[r]);
        }
    }
}

// ---------- kernel 3: out-proj GEMM. 128-row strip/block; Wout prefetch-streamed. ----------
__launch_bounds__(256, 4)
__global__ void oproj(const unsigned short* __restrict__ attn_b,  // [M][128] bf16 (ws)
                      const unsigned short* __restrict__ woutb,
                      const float* __restrict__ bout,
                      float* __restrict__ out, int M) {
    __shared__ __align__(16) unsigned short As[128 * 136];
    const int m0 = blockIdx.x * 128;
    const int tid = threadIdx.x;

    for (int f = tid; f < 2048; f += 256) {          // A tile (zero pad beyond M)
        int t = f >> 4, c = f & 15;
        uint4 w = make_uint4(0u, 0u, 0u, 0u);
        if (m0 + t < M)
            w = *(const uint4*)(attn_b + (size_t)(m0 + t) * DM + c * 8);
        *(uint4*)&As[t * 136 + c * 8] = w;
    }
    __syncthreads();                                  // the ONLY barrier

    const int wave = tid >> 6, lane = tid & 63, quad = lane >> 4, l16 = lane & 15;
    const int mr = wave * 32;
    bf16x8 af[2][4];
    #pragma unroll
    for (int mt = 0; mt < 2; ++mt)
        #pragma unroll
        for (int ks = 0; ks < 4; ++ks)
            af[mt][ks] = *(const bf16x8*)&As[(mr + mt * 16 + l16) * 136 + ks * 32 + quad * 8];

    bf16x8 bp[4];
    #pragma unroll
    for (int ks = 0; ks < 4; ++ks)
        bp[ks] = *(const bf16x8*)(woutb + (size_t)l16 * DM + ks * 32 + quad * 8);

    for (int ct = 0; ct < 8; ++ct) {
        bf16x8 bc[4];
        #pragma unroll
        for (int ks = 0; ks < 4; ++ks) bc[ks] = bp[ks];
        if (ct < 7) {
            const int gn = (ct + 1) * 16 + l16;
            #pragma unroll
            for (int ks = 0; ks < 4; ++ks)
                bp[ks] = *(const bf16x8*)(woutb + (size_t)gn * DM + ks * 32 + quad * 8);
        }
        f32x4 a0 = {0.f, 0.f, 0.f, 0.f}, a1 = {0.f, 0.f, 0.f, 0.f};
        #pragma unroll
        for (int ks = 0; ks < 4; ++ks) {
            a0 = __builtin_amdgcn_mfma_f32_16x16x32_bf16(af[0][ks], bc[ks], a0, 0, 0, 0);
            a1 = __builtin_amdgcn_mfma_f32_16x16x32_bf16(af[1][ks], bc[ks], a1, 0, 0, 0);
        }
        const int gc = ct * 16 + l16;
        const float bias = bout[gc];
        #pragma unroll
        for (int r = 0; r < 4; ++r) {
            int row0 = m0 + mr + quad * 4 + r;
            int row1 = row0 + 16;
            if (row0 < M) out[(size_t)row0 * DM + gc] = a0[r] + bias;
            if (row1 < M) out[(size_t)row1 * DM + gc] = a1[r] + bias;
        }
    }
}

extern "C" void kernel_launch(void* const* d_in, const int* in_sizes, int n_in,
                              void* d_out, int out_size, void* d_ws, size_t ws_size,
                              hipStream_t stream) {
    const float* att_in     = (const float*)d_in[0];
    const float* in_proj_w  = (const float*)d_in[1];
    const float* in_proj_b  = (const float*)d_in[2];
    const float* out_proj_w = (const float*)d_in[3];
    const float* out_proj_b = (const float*)d_in[4];
    const int*   agents     = (const int*)d_in[5];
    const int B = in_sizes[5];
    const int M = out_size / DM;             // total tokens (66560)

    // ws layout (assumes ws_size >= ~17.2 MB):
    //   [0,8192)            offs
    //   [8192,106496)       wqkv bf16
    //   [106496,139264)     wout bf16
    //   [139264, +M*256)    Q bf16, later attn_out bf16 (overwritten in-place by attn)
    int* offs = (int*)d_ws;
    unsigned short* wqkv_bf = (unsigned short*)((char*)d_ws + 8192);
    unsigned short* wout_bf = (unsigned short*)((char*)d_ws + 106496);
    unsigned short* qbuf    = (unsigned short*)((char*)d_ws + 139264);
    unsigned short* kvbuf   = (unsigned short*)d_out;   // [M][256] bf16 == exactly out bytes

    hipLaunchKernelGGL(prep, dim3(65), dim3(256), 0, stream,
                       agents, B, in_proj_w, out_proj_w, offs, wqkv_bf, wout_bf);
    hipLaunchKernelGGL(qkv_gemm, dim3((M + 127) / 128), dim3(256), 0, stream,
                       att_in, wqkv_bf, in_proj_b, qbuf, kvbuf, M);
    hipLaunchKernelGGL(attn, dim3(B), dim3(512), 0, stream,
                       qbuf, kvbuf, agents, offs, M);
    hipLaunchKernelGGL(oproj, dim3((M + 127) / 128), dim3(256), 0, stream,
                       qbuf, wout_bf, out_proj_b, (float*)d_out, M);
}